// Round 5
// baseline (12792.008 us; speedup 1.0000x reference)
//
#include <hip/hip_runtime.h>
#include <math.h>

// STAttentionBlock N=32 C=64 T=400 V=27 S=2 IC=16 — f32 I/O, f32 compute.
// Round 5: round-4 register-column design + fix: wInT fill loop covered only
// 2048/4096 elements (s=1 q/k weights were poison).

#define NN 32
#define TT 400
#define PIX 10800            // T*V
#define NSUV 46656           // N*S*27*27

__device__ __forceinline__ float lrelu(float x) { return x >= 0.f ? x : 0.1f * x; }
__device__ __forceinline__ float4 ld4g(const float* p) { return *reinterpret_cast<const float4*>(p); }

// ---------------------------------------------------------------------------
// k_prep: block 0: pb[sq][c][u28] = b_in + W·pe (PE absorbed into bias)
//         block 1: wInT[(sq*64+cc)*16+c] = w_in[(qk*32+s*16+c)*64+cc]
// ---------------------------------------------------------------------------
__global__ __launch_bounds__(256) void k_prep(
    const float* __restrict__ w_in, const float* __restrict__ b_in,
    float* __restrict__ pb, float* __restrict__ wInT)
{
    const int tid = threadIdx.x;
    if (blockIdx.x == 0) {
        __shared__ float pe[1728];
        for (int idx = tid; idx < 1728; idx += 256) {
            int c = idx / 27, u = idx % 27;
            float div = expf(-0.28782313662425575f * (float)(c >> 1));
            float ang = div * (float)u;
            pe[idx] = (c & 1) ? cosf(ang) : sinf(ang);
        }
        __syncthreads();
        for (int idx = tid; idx < 1792; idx += 256) {
            int u = idx % 28, r = idx / 28, c = r % 16, sq = r / 16;
            if (u >= 27) { pb[idx] = 0.f; continue; }
            int s = sq >> 1, qk = sq & 1, row = qk * 32 + s * 16 + c;
            float acc = b_in[row];
            for (int cc = 0; cc < 64; ++cc) acc += w_in[row * 64 + cc] * pe[cc * 27 + u];
            pb[idx] = acc;
        }
    } else {
        for (int idx = tid; idx < 4096; idx += 256) {   // FIXED: was 2048
            int c = idx & 15, r = idx >> 4, cc = r & 63, sq = r >> 6;
            int s = sq >> 1, qk = sq & 1;
            wInT[idx] = w_in[(qk * 32 + s * 16 + c) * 64 + cc];
        }
    }
}

// ---------------------------------------------------------------------------
// k_wtT: wtT[(kt*64+o)*64+c] = w_t[o*192 + c*3 + kt]  (contiguous-c rows)
// ---------------------------------------------------------------------------
__global__ void k_wtT(const float* __restrict__ w_t, float* __restrict__ wtT)
{
    int i = blockIdx.x * 256 + threadIdx.x;
    if (i >= 12288) return;
    int c = i & 63, o = (i >> 6) & 63, kt = i >> 12;
    wtT[i] = w_t[o * 192 + c * 3 + kt];
}

// ---------------------------------------------------------------------------
// k_scores: grid (25, 2, 32), block 128 (2 waves). Wave: 8 t as 4 pairs.
// lane = (t2, u). q,k in registers; weights via uniform s_load (wInT);
// k exchanged across u-lanes through tiny LDS; scores acc[28] in regs.
// ---------------------------------------------------------------------------
__global__ __launch_bounds__(128) void k_scores(
    const float* __restrict__ x, const float* __restrict__ wInT,
    const float* __restrict__ pb, float* __restrict__ scores)
{
    const int tid = threadIdx.x, wv = tid >> 6, lane = tid & 63;
    const int t2 = lane >> 5, ul = lane & 31;
    const int uc = ul < 26 ? ul : 26;
    const int uu = ul < 27 ? ul : 27;
    const int s = blockIdx.y, n = blockIdx.z;
    const int tw = blockIdx.x * 16 + wv * 8;

    __shared__ __align__(16) float kb[2][2][16 * 28];

    float acc[28];
    #pragma unroll
    for (int v = 0; v < 28; ++v) acc[v] = 0.f;

    const float* pbq = pb + (s * 2 + 0) * 448;
    const float* pbk = pb + (s * 2 + 1) * 448;
    const float* wq  = wInT + (s * 2 + 0) * 1024;
    const float* wk  = wInT + (s * 2 + 1) * 1024;

    for (int it = 0; it < 4; ++it) {
        const int t = tw + it * 2 + t2;
        float q[16], k[16];
        #pragma unroll
        for (int c = 0; c < 16; ++c) { q[c] = pbq[c * 28 + uu]; k[c] = pbk[c * 28 + uu]; }
        for (int cc = 0; cc < 64; ++cc) {
            float xv = x[(size_t)(n * 64 + cc) * PIX + t * 27 + uc];
            #pragma unroll
            for (int c = 0; c < 16; ++c) {
                q[c] += wq[cc * 16 + c] * xv;
                k[c] += wk[cc * 16 + c] * xv;
            }
        }
        #pragma unroll
        for (int ic = 0; ic < 16; ++ic) kb[wv][t2][ic * 28 + uu] = k[ic];
        __syncthreads();
        #pragma unroll
        for (int ic = 0; ic < 16; ++ic) {
            float qv = q[ic];
            #pragma unroll
            for (int v4 = 0; v4 < 7; ++v4) {
                float4 kv = *reinterpret_cast<const float4*>(&kb[wv][t2][ic * 28 + v4 * 4]);
                acc[v4 * 4 + 0] += qv * kv.x;
                acc[v4 * 4 + 1] += qv * kv.y;
                acc[v4 * 4 + 2] += qv * kv.z;
                if (v4 < 6) acc[v4 * 4 + 3] += qv * kv.w;
            }
        }
        __syncthreads();
    }
    #pragma unroll
    for (int v = 0; v < 27; ++v) acc[v] += __shfl_xor(acc[v], 32);
    if (t2 == 0 && ul < 27) {
        float* sb = scores + (size_t)(n * 2 + s) * 729 + ul * 27;
        #pragma unroll
        for (int v = 0; v < 27; ++v) atomicAdd(&sb[v], acc[v]);
    }
}

// ---------------------------------------------------------------------------
// k_att: att = tanh(scores/(IC*T)) * alpha_s + att0
// ---------------------------------------------------------------------------
__global__ void k_att(const float* __restrict__ scores,
                      const float* __restrict__ alphas,
                      const float* __restrict__ att0,
                      float* __restrict__ att)
{
    int i = blockIdx.x * 256 + threadIdx.x;
    if (i >= NSUV) return;
    int r = i % 1458;
    int s = r / 729;
    att[i] = tanhf(scores[i] * (1.f / 6400.f)) * alphas[s] + att0[r];
}

// ---------------------------------------------------------------------------
// k_cde: grid (200, 32), block 128 (2 waves). Wave = one t. lane = (h, v).
// mm/o1 K-dims in per-lane regs (half each, shfl-combined); weights as
// aligned float4 global loads. LDS: per-wave private mm/o1 slices, no barriers.
// ---------------------------------------------------------------------------
__global__ __launch_bounds__(128, 4) void k_cde(
    const float* __restrict__ x, const float* __restrict__ att,
    const float* __restrict__ w_outs, const float* __restrict__ b_outs,
    const float* __restrict__ go1, const float* __restrict__ bo1,
    const float* __restrict__ mo1, const float* __restrict__ vo1,
    const float* __restrict__ w_ff, const float* __restrict__ b_ff,
    const float* __restrict__ gf2, const float* __restrict__ bf2,
    const float* __restrict__ mf2, const float* __restrict__ vf2,
    float* __restrict__ y2out)
{
    const int tid = threadIdx.x, wv = tid >> 6, lane = tid & 63;
    const int h = lane >> 5, vl = lane & 31;
    const int vv = vl < 27 ? vl : 27;       // LDS pad col
    const int vc = vl < 26 ? vl : 26;       // clamped global col
    const int n = blockIdx.y;
    const int t = blockIdx.x * 2 + wv;
    const int hj = h * 32;

    __shared__ float mmh[2][64 * 28];
    __shared__ float o1h[2][64 * 28];
    float* mma = mmh[wv];
    float* o1a = o1h[wv];

    for (int s = 0; s < 2; ++s) {
        // ---- A: mm[s][ch][v] = sum_u x[ch][u] * att[s][u][v] (lane's c-half)
        {
            float ar[27];
            #pragma unroll
            for (int u = 0; u < 27; ++u)
                ar[u] = att[(size_t)n * 1458 + s * 729 + u * 27 + vc];
            for (int c = 0; c < 32; ++c) {
                int ch = hj + c;
                const float* xr = x + (size_t)(n * 64 + ch) * PIX + t * 27;
                float m0 = 0.f, m1 = 0.f;
                #pragma unroll
                for (int u = 0; u < 26; u += 2) {
                    m0 += xr[u] * ar[u];
                    m1 += xr[u + 1] * ar[u + 1];
                }
                m0 += xr[26] * ar[26];
                mma[ch * 28 + vv] = m0 + m1;
            }
        }
        // ---- preload lane's mm half
        float mr[32];
        #pragma unroll
        for (int j = 0; j < 32; ++j) mr[j] = mma[(hj + j) * 28 + vv];
        // ---- B: o-quads, partial over this s-half of K=128
        for (int og = 0; og < 16; ++og) {
            const int o = og * 4;
            const float* w0 = w_outs + (o + 0) * 128 + s * 64 + hj;
            const float* w1 = w_outs + (o + 1) * 128 + s * 64 + hj;
            const float* w2 = w_outs + (o + 2) * 128 + s * 64 + hj;
            const float* w3 = w_outs + (o + 3) * 128 + s * 64 + hj;
            float a0 = 0.f, a1 = 0.f, a2 = 0.f, a3 = 0.f;
            #pragma unroll
            for (int j4 = 0; j4 < 8; ++j4) {
                float4 wa = ld4g(w0 + j4 * 4), wb = ld4g(w1 + j4 * 4);
                float4 wc = ld4g(w2 + j4 * 4), wd = ld4g(w3 + j4 * 4);
                float m0 = mr[j4 * 4 + 0], m1 = mr[j4 * 4 + 1];
                float m2 = mr[j4 * 4 + 2], m3 = mr[j4 * 4 + 3];
                a0 += wa.x * m0 + wa.y * m1 + wa.z * m2 + wa.w * m3;
                a1 += wb.x * m0 + wb.y * m1 + wb.z * m2 + wb.w * m3;
                a2 += wc.x * m0 + wc.y * m1 + wc.z * m2 + wc.w * m3;
                a3 += wd.x * m0 + wd.y * m1 + wd.z * m2 + wd.w * m3;
            }
            a0 += __shfl_xor(a0, 32);
            a1 += __shfl_xor(a1, 32);
            a2 += __shfl_xor(a2, 32);
            a3 += __shfl_xor(a3, 32);
            if (s == 0) {
                o1a[(o + 0) * 28 + vv] = a0;
                o1a[(o + 1) * 28 + vv] = a1;
                o1a[(o + 2) * 28 + vv] = a2;
                o1a[(o + 3) * 28 + vv] = a3;
            } else {
                float acc[4] = { a0, a1, a2, a3 };
                #pragma unroll
                for (int i = 0; i < 4; ++i) {
                    int oo = o + i;
                    float total = o1a[oo * 28 + vv] + acc[i];
                    float inv = go1[oo] * rsqrtf(vo1[oo] + 1e-5f);
                    float val = (total + b_outs[oo]) * inv + (bo1[oo] - mo1[oo] * inv);
                    float res = x[(size_t)(n * 64 + oo) * PIX + t * 27 + vc];
                    o1a[oo * 28 + vv] = lrelu(res + val);
                }
            }
        }
    }
    // ---- C: ff conv over o1 (lane's c-half in regs)
    float o1r[32];
    #pragma unroll
    for (int j = 0; j < 32; ++j) o1r[j] = o1a[(hj + j) * 28 + vv];
    for (int og = 0; og < 16; ++og) {
        const int o = og * 4;
        const float* w0 = w_ff + (o + 0) * 64 + hj;
        const float* w1 = w_ff + (o + 1) * 64 + hj;
        const float* w2 = w_ff + (o + 2) * 64 + hj;
        const float* w3 = w_ff + (o + 3) * 64 + hj;
        float a0 = 0.f, a1 = 0.f, a2 = 0.f, a3 = 0.f;
        #pragma unroll
        for (int j4 = 0; j4 < 8; ++j4) {
            float4 wa = ld4g(w0 + j4 * 4), wb = ld4g(w1 + j4 * 4);
            float4 wc = ld4g(w2 + j4 * 4), wd = ld4g(w3 + j4 * 4);
            float m0 = o1r[j4 * 4 + 0], m1 = o1r[j4 * 4 + 1];
            float m2 = o1r[j4 * 4 + 2], m3 = o1r[j4 * 4 + 3];
            a0 += wa.x * m0 + wa.y * m1 + wa.z * m2 + wa.w * m3;
            a1 += wb.x * m0 + wb.y * m1 + wb.z * m2 + wb.w * m3;
            a2 += wc.x * m0 + wc.y * m1 + wc.z * m2 + wc.w * m3;
            a3 += wd.x * m0 + wd.y * m1 + wd.z * m2 + wd.w * m3;
        }
        a0 += __shfl_xor(a0, 32);
        a1 += __shfl_xor(a1, 32);
        a2 += __shfl_xor(a2, 32);
        a3 += __shfl_xor(a3, 32);
        float acc[4] = { a0, a1, a2, a3 };
        #pragma unroll
        for (int i = 0; i < 4; ++i) {
            int oo = o + i;
            float inv = gf2[oo] * rsqrtf(vf2[oo] + 1e-5f);
            float val = (acc[i] + b_ff[oo]) * inv + (bf2[oo] - mf2[oo] * inv);
            float res = x[(size_t)(n * 64 + oo) * PIX + t * 27 + vc];
            if (vl < 27 && h == 0)
                y2out[(size_t)(n * 64 + oo) * PIX + t * 27 + vl] = lrelu(res + val);
        }
    }
}

// ---------------------------------------------------------------------------
// k_tconv: grid (200, 32), block 128 (2 waves). Wave = one t. lane = (h, v).
// No LDS. yk half-column in regs per kt; weights from pre-transposed wtT.
// ---------------------------------------------------------------------------
__global__ __launch_bounds__(128) void k_tconv(
    const float* __restrict__ y2, const float* __restrict__ wtT,
    const float* __restrict__ b_t,
    const float* __restrict__ gt, const float* __restrict__ btb,
    const float* __restrict__ mt, const float* __restrict__ vt,
    float* __restrict__ out)
{
    const int tid = threadIdx.x, wv = tid >> 6, lane = tid & 63;
    const int h = lane >> 5, vl = lane & 31;
    const int vc = vl < 26 ? vl : 26;
    const int n = blockIdx.y;
    const int t = blockIdx.x * 2 + wv;
    const int hc = h * 32;

    for (int ob = 0; ob < 8; ++ob) {
        float a[8];
        #pragma unroll
        for (int i = 0; i < 8; ++i) a[i] = 0.f;
        for (int kt = 0; kt < 3; ++kt) {
            const int ts = t + kt - 1;
            const bool ok = (ts >= 0 && ts < TT);
            float yk[32];
            #pragma unroll
            for (int c = 0; c < 32; ++c)
                yk[c] = ok ? y2[(size_t)(n * 64 + hc + c) * PIX + ts * 27 + vc] : 0.f;
            const float* wb = wtT + (kt * 64 + ob * 8) * 64 + hc;
            #pragma unroll
            for (int i = 0; i < 8; ++i) {
                const float* wr = wb + i * 64;
                float s0 = 0.f, s1 = 0.f;
                #pragma unroll
                for (int c4 = 0; c4 < 8; ++c4) {
                    float4 w4 = ld4g(wr + c4 * 4);
                    s0 += w4.x * yk[c4 * 4 + 0] + w4.y * yk[c4 * 4 + 1];
                    s1 += w4.z * yk[c4 * 4 + 2] + w4.w * yk[c4 * 4 + 3];
                }
                a[i] += s0 + s1;
            }
        }
        #pragma unroll
        for (int i = 0; i < 8; ++i) {
            a[i] += __shfl_xor(a[i], 32);
            int o = ob * 8 + i;
            float inv = gt[o] * rsqrtf(vt[o] + 1e-5f);
            float val = (a[i] + b_t[o]) * inv + (btb[o] - mt[o] * inv);
            float res = y2[(size_t)(n * 64 + o) * PIX + t * 27 + vc];
            if (vl < 27 && h == 0)
                out[(size_t)(n * 64 + o) * PIX + t * 27 + vl] = lrelu(res + val);
        }
    }
}

// ---------------------------------------------------------------------------
extern "C" void kernel_launch(void* const* d_in, const int* in_sizes, int n_in,
                              void* d_out, int out_size, void* d_ws, size_t ws_size,
                              hipStream_t stream)
{
    const float* x      = (const float*)d_in[0];
    const float* w_in   = (const float*)d_in[1];
    const float* b_in   = (const float*)d_in[2];
    const float* alphas = (const float*)d_in[3];
    const float* att0   = (const float*)d_in[4];
    const float* w_outs = (const float*)d_in[5];
    const float* b_outs = (const float*)d_in[6];
    const float* bog    = (const float*)d_in[7];
    const float* bob    = (const float*)d_in[8];
    const float* bom    = (const float*)d_in[9];
    const float* bov    = (const float*)d_in[10];
    const float* w_ff   = (const float*)d_in[11];
    const float* b_ff   = (const float*)d_in[12];
    const float* bfg    = (const float*)d_in[13];
    const float* bfb    = (const float*)d_in[14];
    const float* bfm    = (const float*)d_in[15];
    const float* bfv    = (const float*)d_in[16];
    const float* w_t    = (const float*)d_in[17];
    const float* b_t    = (const float*)d_in[18];
    const float* btg    = (const float*)d_in[19];
    const float* btb    = (const float*)d_in[20];
    const float* btm    = (const float*)d_in[21];
    const float* btv    = (const float*)d_in[22];

    // ws layout (f32): [scores 46656][att 46656][y2 22118400]
    // att region doubles as pb(1792)+wInT(4096) BEFORE k_att runs;
    // scores region doubles as wtT(12288) AFTER k_att consumed it.
    float* scores = (float*)d_ws;
    float* attw   = scores + NSUV;
    float* y2     = attw + NSUV;
    float* pb     = attw;            // alias: dead once k_att writes attw
    float* wInT   = attw + 1792;     // alias
    float* wtT    = scores;          // alias: valid after k_att

    hipMemsetAsync(scores, 0, NSUV * sizeof(float), stream);

    k_prep<<<2, 256, 0, stream>>>(w_in, b_in, pb, wInT);
    k_scores<<<dim3(25, 2, NN), 128, 0, stream>>>(x, wInT, pb, scores);
    k_att<<<(NSUV + 255) / 256, 256, 0, stream>>>(scores, alphas, att0, attw);
    k_wtT<<<48, 256, 0, stream>>>(w_t, wtT);
    k_cde<<<dim3(200, NN), 128, 0, stream>>>(x, attw, w_outs, b_outs,
                                             bog, bob, bom, bov,
                                             w_ff, b_ff, bfg, bfb, bfm, bfv, y2);
    k_tconv<<<dim3(200, NN), 128, 0, stream>>>(y2, wtT, b_t, btg, btb, btm, btv,
                                               (float*)d_out);
}